// Round 5
// baseline (246.436 us; speedup 1.0000x reference)
//
#include <hip/hip_runtime.h>
#include <hip/hip_fp16.h>

#define ND 100000   // N_NODES
#define NE 50000    // N_EDGES
#define AR 32       // EDGE_ARITY
#define DG 16       // NODE_DEG
#define D  128      // D_IN == D_OUT == TV

typedef _Float16 half8_t __attribute__((ext_vector_type(8)));
typedef _Float16 half4_t __attribute__((ext_vector_type(4)));
typedef float    f32x4_t __attribute__((ext_vector_type(4)));
typedef int      i32x4_t __attribute__((ext_vector_type(4)));   // NT-loadable int4

#define APAD 136   // LDS A-row stride (halves): 16B-aligned, 2-way aliasing free

// ---------------------------------------------------------------------------
// K0: fused prep.  blocks 0..63: w1,w2 -> fragment-major fp16.
//     block 64: inter_nw = mean(cos(w3 rows, w3[0])).
// ---------------------------------------------------------------------------
__global__ __launch_bounds__(256) void k_prep(const float* __restrict__ w1,
                                              const float* __restrict__ w2,
                                              const float* __restrict__ w3,
                                              _Float16* __restrict__ w1f,
                                              _Float16* __restrict__ w2f,
                                              float* __restrict__ inter_out) {
    if (blockIdx.x == 64) {
        __shared__ float red[128];
        int j = threadIdx.x;
        if (j < 128) {
            float dot = 0.f, sq = 0.f, sq0 = 0.f;
            #pragma unroll 8
            for (int k = 0; k < D; ++k) {
                float wj = w3[j * D + k];
                float w0 = w3[k];
                dot += wj * w0;
                sq  += wj * wj;
                sq0 += w0 * w0;
            }
            red[j] = dot / (sqrtf(sq0) * sqrtf(sq));
        }
        __syncthreads();
        if (j == 0) {
            float s = 0.f;
            for (int i = 0; i < 128; ++i) s += red[i];
            inter_out[0] = s / 128.f;
        }
        return;
    }
    int o = blockIdx.x * 256 + threadIdx.x;   // 0..16383
    int j    = o & 7;
    int lane = (o >> 3) & 63;
    int frag = o >> 9;                        // 0..31
    int ntile = frag >> 2, ktile = frag & 3;
    int n = ntile * 16 + (lane & 15);
    int k = ktile * 32 + (lane >> 4) * 8 + j;
    w1f[o] = (_Float16)w1[k * D + n];
    w2f[o] = (_Float16)w2[k * D + n];
}

// ---------------------------------------------------------------------------
// K1: xw = (x @ w1) * inter_nw via MFMA (transposed-operand epilogue).
// Output layout: SLICE-MAJOR xws[4][ND][32] halfs: 64 B rows per slice so a
// gather quad reads one FULL 64 B line (minimum line-request count: 410 MB
// of gather volume / 64 B = 6.4M lines -- reached in round 4).
// ---------------------------------------------------------------------------
__global__ __launch_bounds__(256) void k_xw(const float* __restrict__ x,
                                            const _Float16* __restrict__ w1f_g,
                                            const float* __restrict__ inter_p,
                                            _Float16* __restrict__ xws) {
    __shared__ _Float16 wfrag[D * D];     // 32 KB, fragment-major
    __shared__ _Float16 xs[64 * APAD];    // 17 KB
    int t = threadIdx.x;
    {
        const float4* src = (const float4*)w1f_g;
        float4* dst = (float4*)wfrag;
        #pragma unroll
        for (int i = 0; i < 8; ++i) dst[i * 256 + t] = src[i * 256 + t];
    }
    int rowbase = blockIdx.x * 64;
    #pragma unroll
    for (int p = 0; p < 8; ++p) {
        int idx = p * 1024 + t * 4;
        int r = idx >> 7, c = idx & 127;
        int grow = rowbase + r;
        float4 v = make_float4(0.f, 0.f, 0.f, 0.f);
        if (grow < ND) v = ((const float4*)x)[(size_t)grow * 32 + (c >> 2)];
        half4_t h = { (_Float16)v.x, (_Float16)v.y, (_Float16)v.z, (_Float16)v.w };
        *(half4_t*)&xs[r * APAD + c] = h;
    }
    __syncthreads();

    int wave = t >> 6, lane = t & 63;
    int quad = lane >> 4, l15 = lane & 15;
    int m0 = wave * 16;
    float inter = inter_p[0];

    half8_t a[4];
    #pragma unroll
    for (int kt = 0; kt < 4; ++kt)
        a[kt] = *(const half8_t*)&xs[(m0 + l15) * APAD + kt * 32 + quad * 8];

    int grow = rowbase + m0 + l15;
    #pragma unroll
    for (int nt = 0; nt < 8; ++nt) {
        f32x4_t acc = {0.f, 0.f, 0.f, 0.f};
        #pragma unroll
        for (int kt = 0; kt < 4; ++kt) {
            half8_t b = *(const half8_t*)&wfrag[((nt * 4 + kt) * 64 + lane) * 8];
            acc = __builtin_amdgcn_mfma_f32_16x16x32_f16(b, a[kt], acc, 0, 0, 0);
        }
        half4_t hv = { (_Float16)(acc[0] * inter), (_Float16)(acc[1] * inter),
                       (_Float16)(acc[2] * inter), (_Float16)(acc[3] * inter) };
        if (grow < ND) {  // slice nt>>1, col-in-slice (nt&1)*16 + quad*4
            half4_t* dst = (half4_t*)(xws + ((size_t)(nt >> 1) * ND + grow) * 32
                                          + (nt & 1) * 16 + quad * 4);
            __builtin_nontemporal_store(hv, dst);
        }
    }
}

// ---------------------------------------------------------------------------
// K2a: edge gather, slice s = blockIdx&3.  Quad-coalesced 64 B rows (minimum
// line requests).  ROUND-5: deep per-wave MLP -- batch 16 gather loads before
// consuming any (compiler emits counted vmcnt; first FMA overlaps 15 loads
// still in flight).  Round-4's VGPR=36 showed only ~4 loads in flight/thread.
// ---------------------------------------------------------------------------
__global__ __launch_bounds__(256, 4) void k_gather_e(const int* __restrict__ seq,
                                                     const _Float16* __restrict__ xws,
                                                     _Float16* __restrict__ ea) {
    int t = threadIdx.x;
    int s = blockIdx.x & 3;
    int g = blockIdx.x >> 2;
    int e = t >> 2, part = t & 3;                 // edge 0..63, 16-B chunk 0..3
    int eg = g * 64 + e;
    int egs = min(eg, NE - 1);

    const i32x4_t* sp = (const i32x4_t*)(seq + (size_t)egs * AR);
    i32x4_t q0 = __builtin_nontemporal_load(sp + 0);
    i32x4_t q1 = __builtin_nontemporal_load(sp + 1);
    i32x4_t q2 = __builtin_nontemporal_load(sp + 2);
    i32x4_t q3 = __builtin_nontemporal_load(sp + 3);
    i32x4_t q4 = __builtin_nontemporal_load(sp + 4);
    i32x4_t q5 = __builtin_nontemporal_load(sp + 5);
    i32x4_t q6 = __builtin_nontemporal_load(sp + 6);
    i32x4_t q7 = __builtin_nontemporal_load(sp + 7);
    int idxs[32] = { q0[0], q0[1], q0[2], q0[3], q1[0], q1[1], q1[2], q1[3],
                     q2[0], q2[1], q2[2], q2[3], q3[0], q3[1], q3[2], q3[3],
                     q4[0], q4[1], q4[2], q4[3], q5[0], q5[1], q5[2], q5[3],
                     q6[0], q6[1], q6[2], q6[3], q7[0], q7[1], q7[2], q7[3] };
    int cnt = 0;
    #pragma unroll
    for (int j = 0; j < AR; ++j) cnt += (idxs[j] > 0);
    bool allv = (cnt == 0);
    float wv = 1.f / (float)(allv ? AR : cnt);

    const _Float16* tab = xws + (size_t)s * ND * 32 + part * 8;

    float acc[8] = {};
    #pragma unroll
    for (int h = 0; h < 2; ++h) {
        half8_t v[16];                            // 64 VGPRs: 16 loads in flight
        #pragma unroll
        for (int i = 0; i < 16; ++i)
            v[i] = *(const half8_t*)(tab + (size_t)idxs[h * 16 + i] * 32);
        #pragma unroll
        for (int i = 0; i < 16; ++i) {
            float w = (allv | (idxs[h * 16 + i] > 0)) ? wv : 0.f;
            #pragma unroll
            for (int jj = 0; jj < 8; ++jj)
                acc[jj] = fmaf(w, (float)v[i][jj], acc[jj]);
        }
    }
    if (eg < NE) {
        half8_t h;
        #pragma unroll
        for (int jj = 0; jj < 8; ++jj) h[jj] = (_Float16)fmaxf(acc[jj], 0.f);
        __builtin_nontemporal_store(h, (half8_t*)(ea + (size_t)eg * D + s * 32 + part * 8));
    }
}

// ---------------------------------------------------------------------------
// K2b: e1 = ea @ w2 via MFMA; output SLICE-MAJOR e1s[4][NE][32] halfs
// (64 B rows per slice, 3.2 MB/slice) for the sliced node gather.
// ---------------------------------------------------------------------------
__global__ __launch_bounds__(256) void k_gemm_e(const _Float16* __restrict__ ea,
                                                const _Float16* __restrict__ w2f_g,
                                                _Float16* __restrict__ e1s) {
    __shared__ _Float16 wfrag[D * D];
    __shared__ _Float16 et[64 * APAD];
    int t = threadIdx.x;
    {
        const float4* src = (const float4*)w2f_g;
        float4* dst = (float4*)wfrag;
        #pragma unroll
        for (int i = 0; i < 8; ++i) dst[i * 256 + t] = src[i * 256 + t];
    }
    int rowbase = blockIdx.x * 64;
    #pragma unroll
    for (int p = 0; p < 4; ++p) {
        int hidx = p * 2048 + t * 8;
        int r = hidx >> 7, c = hidx & 127;
        int grow = rowbase + r;
        int gs = (grow < NE) ? grow : (NE - 1);
        half8_t v = *(const half8_t*)(ea + (size_t)gs * D + c);
        *(half8_t*)&et[r * APAD + c] = v;
    }
    __syncthreads();

    int wave = t >> 6, lane = t & 63;
    int quad = lane >> 4, l15 = lane & 15;
    int m0 = wave * 16;

    half8_t a[4];
    #pragma unroll
    for (int kt = 0; kt < 4; ++kt)
        a[kt] = *(const half8_t*)&et[(m0 + l15) * APAD + kt * 32 + quad * 8];

    int grow = rowbase + m0 + l15;
    #pragma unroll
    for (int nt = 0; nt < 8; ++nt) {
        f32x4_t acc = {0.f, 0.f, 0.f, 0.f};
        #pragma unroll
        for (int kt = 0; kt < 4; ++kt) {
            half8_t b = *(const half8_t*)&wfrag[((nt * 4 + kt) * 64 + lane) * 8];
            acc = __builtin_amdgcn_mfma_f32_16x16x32_f16(b, a[kt], acc, 0, 0, 0);
        }
        half4_t hv = { (_Float16)acc[0], (_Float16)acc[1],
                       (_Float16)acc[2], (_Float16)acc[3] };
        if (grow < NE)   // slice nt>>1, col-in-slice (nt&1)*16 + quad*4
            *(half4_t*)(e1s + ((size_t)(nt >> 1) * NE + grow) * 32
                            + (nt & 1) * 16 + quad * 4) = hv;
    }
}

// ---------------------------------------------------------------------------
// K3: node gather, slice s = blockIdx&3 (3.2 MB/slice, L2-resident).
// LDS-free, quad-coalesced 64 B rows.  ROUND-5: all 16 gather loads batched
// before any consumption (deep per-wave MLP, same rationale as k_gather_e).
// ---------------------------------------------------------------------------
__global__ __launch_bounds__(256, 4) void k_gather_n(const int* __restrict__ useq,
                                                     const _Float16* __restrict__ e1s,
                                                     float* __restrict__ out) {
    int t = threadIdx.x;
    int s = blockIdx.x & 3;
    int g = blockIdx.x >> 2;
    int n = t >> 2, part = t & 3;                 // node-in-block, 16-B chunk
    int ng = g * 64 + n;
    int ns = min(ng, ND - 1);

    const i32x4_t* up = (const i32x4_t*)(useq + (size_t)ns * DG);
    i32x4_t q0 = __builtin_nontemporal_load(up + 0);
    i32x4_t q1 = __builtin_nontemporal_load(up + 1);
    i32x4_t q2 = __builtin_nontemporal_load(up + 2);
    i32x4_t q3 = __builtin_nontemporal_load(up + 3);
    int idxs[16] = { q0[0], q0[1], q0[2], q0[3], q1[0], q1[1], q1[2], q1[3],
                     q2[0], q2[1], q2[2], q2[3], q3[0], q3[1], q3[2], q3[3] };
    int cnt = 0;
    #pragma unroll
    for (int j = 0; j < DG; ++j) cnt += (idxs[j] > 0);
    bool allv = (cnt == 0);
    float wv = 1.f / (float)(allv ? DG : cnt);

    const _Float16* tab = e1s + (size_t)s * NE * 32 + part * 8;

    float acc[8] = {};
    {
        half8_t v[16];                            // 64 VGPRs: 16 loads in flight
        #pragma unroll
        for (int i = 0; i < 16; ++i)
            v[i] = *(const half8_t*)(tab + (size_t)idxs[i] * 32);
        #pragma unroll
        for (int i = 0; i < 16; ++i) {
            float w = (allv | (idxs[i] > 0)) ? wv : 0.f;
            #pragma unroll
            for (int jj = 0; jj < 8; ++jj)
                acc[jj] = fmaf(w, (float)v[i][jj], acc[jj]);
        }
    }
    if (ng < ND) {
        f32x4_t o0 = { acc[0], acc[1], acc[2], acc[3] };
        f32x4_t o1 = { acc[4], acc[5], acc[6], acc[7] };
        f32x4_t* p = (f32x4_t*)(out + (size_t)ng * D + s * 32 + part * 8);
        __builtin_nontemporal_store(o0, p);
        __builtin_nontemporal_store(o1, p + 1);
    }
}

// ---------------------------------------------------------------------------
extern "C" void kernel_launch(void* const* d_in, const int* in_sizes, int n_in,
                              void* d_out, int out_size, void* d_ws, size_t ws_size,
                              hipStream_t stream) {
    const float* x    = (const float*)d_in[0];
    const int*   seq  = (const int*)d_in[1];
    const int*   useq = (const int*)d_in[2];
    // d_in[3] = TextVector: unused (reference overwrites it with weight3[0])
    const float* w1   = (const float*)d_in[4];
    const float* w2   = (const float*)d_in[5];
    const float* w3   = (const float*)d_in[6];
    float* out = (float*)d_out;

    // Scratch: d_out hosts xws [0,25.6M) and ea [25.6M,38.4M) (dead before
    // k_gather_n overwrites d_out). d_ws: inter | w1f 32K | w2f 32K | e1s 12.8M.
    _Float16* xws   = (_Float16*)d_out;
    _Float16* ea    = (_Float16*)d_out + (size_t)ND * D;
    float*    inter = (float*)d_ws;
    _Float16* w1f   = (_Float16*)((char*)d_ws + 256);
    _Float16* w2f   = (_Float16*)((char*)d_ws + 256 + 32768);
    _Float16* e1s   = (_Float16*)((char*)d_ws + 256 + 65536);

    int eg_grp = (NE + 63) / 64;         // 782
    int ng_grp = (ND + 63) / 64;         // 1563

    hipLaunchKernelGGL(k_prep,     dim3(65),             dim3(256), 0, stream, w1, w2, w3, w1f, w2f, inter);
    hipLaunchKernelGGL(k_xw,       dim3((ND + 63) / 64), dim3(256), 0, stream, x, w1f, inter, xws);
    hipLaunchKernelGGL(k_gather_e, dim3(eg_grp * 4),     dim3(256), 0, stream, seq, xws, ea);
    hipLaunchKernelGGL(k_gemm_e,   dim3((NE + 63) / 64), dim3(256), 0, stream, ea, w2f, e1s);
    hipLaunchKernelGGL(k_gather_n, dim3(ng_grp * 4),     dim3(256), 0, stream, useq, e1s, out);
}

// Round 6
// 236.602 us; speedup vs baseline: 1.0416x; 1.0416x over previous
//
#include <hip/hip_runtime.h>
#include <hip/hip_fp16.h>

#define ND 100000   // N_NODES
#define NE 50000    // N_EDGES
#define AR 32       // EDGE_ARITY
#define DG 16       // NODE_DEG
#define D  128      // D_IN == D_OUT == TV

typedef _Float16 half8_t __attribute__((ext_vector_type(8)));
typedef _Float16 half4_t __attribute__((ext_vector_type(4)));
typedef float    f32x4_t __attribute__((ext_vector_type(4)));
typedef int      i32x4_t __attribute__((ext_vector_type(4)));   // NT-loadable int4

#define APAD 136   // LDS A-row stride (halves): 16B-aligned, 2-way aliasing free

// ---------------------------------------------------------------------------
// Gather helpers: statically-indexed 8-load batches (rule #20: every access
// compile-time constant so arrays live in VGPRs).  Issue order is pinned with
// sched_barrier(0) at the call sites -- round-5 lesson: without the pin the
// compiler sinks the batch back to depth ~4 (VGPR stayed 36).
// ---------------------------------------------------------------------------
template<int OFF, int NI>
__device__ __forceinline__ void g_load8(half8_t (&v)[8], const int (&idxs)[NI],
                                        const _Float16* __restrict__ tab) {
    #pragma unroll
    for (int i = 0; i < 8; ++i)
        v[i] = *(const half8_t*)(tab + (size_t)idxs[OFF + i] * 32);
}

template<int OFF, int NI>
__device__ __forceinline__ void g_acc8(const half8_t (&v)[8], const int (&idxs)[NI],
                                       bool allv, float wv, float (&acc)[8]) {
    #pragma unroll
    for (int i = 0; i < 8; ++i) {
        float w = (allv | (idxs[OFF + i] > 0)) ? wv : 0.f;
        #pragma unroll
        for (int jj = 0; jj < 8; ++jj)
            acc[jj] = fmaf(w, (float)v[i][jj], acc[jj]);
    }
}

// ---------------------------------------------------------------------------
// K0: fused prep.  blocks 0..63: w1,w2 -> fragment-major fp16.
//     block 64: inter_nw = mean(cos(w3 rows, w3[0])).
// ---------------------------------------------------------------------------
__global__ __launch_bounds__(256) void k_prep(const float* __restrict__ w1,
                                              const float* __restrict__ w2,
                                              const float* __restrict__ w3,
                                              _Float16* __restrict__ w1f,
                                              _Float16* __restrict__ w2f,
                                              float* __restrict__ inter_out) {
    if (blockIdx.x == 64) {
        __shared__ float red[128];
        int j = threadIdx.x;
        if (j < 128) {
            float dot = 0.f, sq = 0.f, sq0 = 0.f;
            #pragma unroll 8
            for (int k = 0; k < D; ++k) {
                float wj = w3[j * D + k];
                float w0 = w3[k];
                dot += wj * w0;
                sq  += wj * wj;
                sq0 += w0 * w0;
            }
            red[j] = dot / (sqrtf(sq0) * sqrtf(sq));
        }
        __syncthreads();
        if (j == 0) {
            float s = 0.f;
            for (int i = 0; i < 128; ++i) s += red[i];
            inter_out[0] = s / 128.f;
        }
        return;
    }
    int o = blockIdx.x * 256 + threadIdx.x;   // 0..16383
    int j    = o & 7;
    int lane = (o >> 3) & 63;
    int frag = o >> 9;                        // 0..31
    int ntile = frag >> 2, ktile = frag & 3;
    int n = ntile * 16 + (lane & 15);
    int k = ktile * 32 + (lane >> 4) * 8 + j;
    w1f[o] = (_Float16)w1[k * D + n];
    w2f[o] = (_Float16)w2[k * D + n];
}

// ---------------------------------------------------------------------------
// K1: xw = (x @ w1) * inter_nw via MFMA (transposed-operand epilogue).
// Output layout: SLICE-MAJOR xws[4][ND][32] halfs: 64 B rows per slice so a
// gather quad reads one FULL 64 B line (minimum line-request count).
// Stores are NORMAL (round-4/5 lesson: NT stores demoted xws from cache,
// FETCH_SIZE tripled and the whole pipeline slowed ~15 us).
// ---------------------------------------------------------------------------
__global__ __launch_bounds__(256) void k_xw(const float* __restrict__ x,
                                            const _Float16* __restrict__ w1f_g,
                                            const float* __restrict__ inter_p,
                                            _Float16* __restrict__ xws) {
    __shared__ _Float16 wfrag[D * D];     // 32 KB, fragment-major
    __shared__ _Float16 xs[64 * APAD];    // 17 KB
    int t = threadIdx.x;
    {
        const float4* src = (const float4*)w1f_g;
        float4* dst = (float4*)wfrag;
        #pragma unroll
        for (int i = 0; i < 8; ++i) dst[i * 256 + t] = src[i * 256 + t];
    }
    int rowbase = blockIdx.x * 64;
    #pragma unroll
    for (int p = 0; p < 8; ++p) {
        int idx = p * 1024 + t * 4;
        int r = idx >> 7, c = idx & 127;
        int grow = rowbase + r;
        float4 v = make_float4(0.f, 0.f, 0.f, 0.f);
        if (grow < ND) v = ((const float4*)x)[(size_t)grow * 32 + (c >> 2)];
        half4_t h = { (_Float16)v.x, (_Float16)v.y, (_Float16)v.z, (_Float16)v.w };
        *(half4_t*)&xs[r * APAD + c] = h;
    }
    __syncthreads();

    int wave = t >> 6, lane = t & 63;
    int quad = lane >> 4, l15 = lane & 15;
    int m0 = wave * 16;
    float inter = inter_p[0];

    half8_t a[4];
    #pragma unroll
    for (int kt = 0; kt < 4; ++kt)
        a[kt] = *(const half8_t*)&xs[(m0 + l15) * APAD + kt * 32 + quad * 8];

    int grow = rowbase + m0 + l15;
    #pragma unroll
    for (int nt = 0; nt < 8; ++nt) {
        f32x4_t acc = {0.f, 0.f, 0.f, 0.f};
        #pragma unroll
        for (int kt = 0; kt < 4; ++kt) {
            half8_t b = *(const half8_t*)&wfrag[((nt * 4 + kt) * 64 + lane) * 8];
            acc = __builtin_amdgcn_mfma_f32_16x16x32_f16(b, a[kt], acc, 0, 0, 0);
        }
        half4_t hv = { (_Float16)(acc[0] * inter), (_Float16)(acc[1] * inter),
                       (_Float16)(acc[2] * inter), (_Float16)(acc[3] * inter) };
        if (grow < ND)   // slice nt>>1, col-in-slice (nt&1)*16 + quad*4
            *(half4_t*)(xws + ((size_t)(nt >> 1) * ND + grow) * 32
                            + (nt & 1) * 16 + quad * 4) = hv;
    }
}

// ---------------------------------------------------------------------------
// K2a: edge gather, slice s = blockIdx&3, quad-coalesced 64 B rows (minimum
// line requests).  ROUND-6: FORCED 8-deep double-buffered pipeline --
// sched_barrier(0) pins the issue order {8 loads}{8 loads}|{8 fma}{8 loads}|
// ... so 8-16 loads stay in flight per thread (round-4/5: compiler capped
// depth at ~4, VGPR=36).
// ---------------------------------------------------------------------------
__global__ __launch_bounds__(256, 4) void k_gather_e(const int* __restrict__ seq,
                                                     const _Float16* __restrict__ xws,
                                                     _Float16* __restrict__ ea) {
    int t = threadIdx.x;
    int s = blockIdx.x & 3;
    int g = blockIdx.x >> 2;
    int e = t >> 2, part = t & 3;                 // edge 0..63, 16-B chunk 0..3
    int eg = g * 64 + e;
    int egs = min(eg, NE - 1);

    const i32x4_t* sp = (const i32x4_t*)(seq + (size_t)egs * AR);
    i32x4_t q0 = __builtin_nontemporal_load(sp + 0);
    i32x4_t q1 = __builtin_nontemporal_load(sp + 1);
    i32x4_t q2 = __builtin_nontemporal_load(sp + 2);
    i32x4_t q3 = __builtin_nontemporal_load(sp + 3);
    i32x4_t q4 = __builtin_nontemporal_load(sp + 4);
    i32x4_t q5 = __builtin_nontemporal_load(sp + 5);
    i32x4_t q6 = __builtin_nontemporal_load(sp + 6);
    i32x4_t q7 = __builtin_nontemporal_load(sp + 7);
    int idxs[32] = { q0[0], q0[1], q0[2], q0[3], q1[0], q1[1], q1[2], q1[3],
                     q2[0], q2[1], q2[2], q2[3], q3[0], q3[1], q3[2], q3[3],
                     q4[0], q4[1], q4[2], q4[3], q5[0], q5[1], q5[2], q5[3],
                     q6[0], q6[1], q6[2], q6[3], q7[0], q7[1], q7[2], q7[3] };
    int cnt = 0;
    #pragma unroll
    for (int j = 0; j < AR; ++j) cnt += (idxs[j] > 0);
    bool allv = (cnt == 0);
    float wv = 1.f / (float)(allv ? AR : cnt);

    const _Float16* tab = xws + (size_t)s * ND * 32 + part * 8;

    float acc[8] = {};
    half8_t va[8], vb[8];
    g_load8<0>(va, idxs, tab);                    // 8 in flight
    g_load8<8>(vb, idxs, tab);                    // 16 in flight
    __builtin_amdgcn_sched_barrier(0);
    g_acc8<0>(va, idxs, allv, wv, acc);           // waits vmcnt(8)
    g_load8<16>(va, idxs, tab);                   // back to 16 in flight
    __builtin_amdgcn_sched_barrier(0);
    g_acc8<8>(vb, idxs, allv, wv, acc);
    g_load8<24>(vb, idxs, tab);
    __builtin_amdgcn_sched_barrier(0);
    g_acc8<16>(va, idxs, allv, wv, acc);
    g_acc8<24>(vb, idxs, allv, wv, acc);

    if (eg < NE) {
        half8_t h;
        #pragma unroll
        for (int jj = 0; jj < 8; ++jj) h[jj] = (_Float16)fmaxf(acc[jj], 0.f);
        __builtin_nontemporal_store(h, (half8_t*)(ea + (size_t)eg * D + s * 32 + part * 8));
    }
}

// ---------------------------------------------------------------------------
// K2b: e1 = ea @ w2 via MFMA; output SLICE-MAJOR e1s[4][NE][32] halfs
// (64 B rows per slice, 3.2 MB/slice) for the sliced node gather.
// ---------------------------------------------------------------------------
__global__ __launch_bounds__(256) void k_gemm_e(const _Float16* __restrict__ ea,
                                                const _Float16* __restrict__ w2f_g,
                                                _Float16* __restrict__ e1s) {
    __shared__ _Float16 wfrag[D * D];
    __shared__ _Float16 et[64 * APAD];
    int t = threadIdx.x;
    {
        const float4* src = (const float4*)w2f_g;
        float4* dst = (float4*)wfrag;
        #pragma unroll
        for (int i = 0; i < 8; ++i) dst[i * 256 + t] = src[i * 256 + t];
    }
    int rowbase = blockIdx.x * 64;
    #pragma unroll
    for (int p = 0; p < 4; ++p) {
        int hidx = p * 2048 + t * 8;
        int r = hidx >> 7, c = hidx & 127;
        int grow = rowbase + r;
        int gs = (grow < NE) ? grow : (NE - 1);
        half8_t v = *(const half8_t*)(ea + (size_t)gs * D + c);
        *(half8_t*)&et[r * APAD + c] = v;
    }
    __syncthreads();

    int wave = t >> 6, lane = t & 63;
    int quad = lane >> 4, l15 = lane & 15;
    int m0 = wave * 16;

    half8_t a[4];
    #pragma unroll
    for (int kt = 0; kt < 4; ++kt)
        a[kt] = *(const half8_t*)&et[(m0 + l15) * APAD + kt * 32 + quad * 8];

    int grow = rowbase + m0 + l15;
    #pragma unroll
    for (int nt = 0; nt < 8; ++nt) {
        f32x4_t acc = {0.f, 0.f, 0.f, 0.f};
        #pragma unroll
        for (int kt = 0; kt < 4; ++kt) {
            half8_t b = *(const half8_t*)&wfrag[((nt * 4 + kt) * 64 + lane) * 8];
            acc = __builtin_amdgcn_mfma_f32_16x16x32_f16(b, a[kt], acc, 0, 0, 0);
        }
        half4_t hv = { (_Float16)acc[0], (_Float16)acc[1],
                       (_Float16)acc[2], (_Float16)acc[3] };
        if (grow < NE)   // slice nt>>1, col-in-slice (nt&1)*16 + quad*4
            *(half4_t*)(e1s + ((size_t)(nt >> 1) * NE + grow) * 32
                            + (nt & 1) * 16 + quad * 4) = hv;
    }
}

// ---------------------------------------------------------------------------
// K3: node gather, slice s = blockIdx&3 (3.2 MB/slice, L2-resident).
// LDS-free, quad-coalesced 64 B rows.  ROUND-6: forced 16-deep load batch
// (sched_barrier pin), then consume.
// ---------------------------------------------------------------------------
__global__ __launch_bounds__(256, 4) void k_gather_n(const int* __restrict__ useq,
                                                     const _Float16* __restrict__ e1s,
                                                     float* __restrict__ out) {
    int t = threadIdx.x;
    int s = blockIdx.x & 3;
    int g = blockIdx.x >> 2;
    int n = t >> 2, part = t & 3;                 // node-in-block, 16-B chunk
    int ng = g * 64 + n;
    int ns = min(ng, ND - 1);

    const i32x4_t* up = (const i32x4_t*)(useq + (size_t)ns * DG);
    i32x4_t q0 = __builtin_nontemporal_load(up + 0);
    i32x4_t q1 = __builtin_nontemporal_load(up + 1);
    i32x4_t q2 = __builtin_nontemporal_load(up + 2);
    i32x4_t q3 = __builtin_nontemporal_load(up + 3);
    int idxs[16] = { q0[0], q0[1], q0[2], q0[3], q1[0], q1[1], q1[2], q1[3],
                     q2[0], q2[1], q2[2], q2[3], q3[0], q3[1], q3[2], q3[3] };
    int cnt = 0;
    #pragma unroll
    for (int j = 0; j < DG; ++j) cnt += (idxs[j] > 0);
    bool allv = (cnt == 0);
    float wv = 1.f / (float)(allv ? DG : cnt);

    const _Float16* tab = e1s + (size_t)s * NE * 32 + part * 8;

    float acc[8] = {};
    half8_t va[8], vb[8];
    g_load8<0>(va, idxs, tab);                    // 8 in flight
    g_load8<8>(vb, idxs, tab);                    // 16 in flight
    __builtin_amdgcn_sched_barrier(0);
    g_acc8<0>(va, idxs, allv, wv, acc);
    g_acc8<8>(vb, idxs, allv, wv, acc);

    if (ng < ND) {
        f32x4_t o0 = { acc[0], acc[1], acc[2], acc[3] };
        f32x4_t o1 = { acc[4], acc[5], acc[6], acc[7] };
        f32x4_t* p = (f32x4_t*)(out + (size_t)ng * D + s * 32 + part * 8);
        __builtin_nontemporal_store(o0, p);
        __builtin_nontemporal_store(o1, p + 1);
    }
}

// ---------------------------------------------------------------------------
extern "C" void kernel_launch(void* const* d_in, const int* in_sizes, int n_in,
                              void* d_out, int out_size, void* d_ws, size_t ws_size,
                              hipStream_t stream) {
    const float* x    = (const float*)d_in[0];
    const int*   seq  = (const int*)d_in[1];
    const int*   useq = (const int*)d_in[2];
    // d_in[3] = TextVector: unused (reference overwrites it with weight3[0])
    const float* w1   = (const float*)d_in[4];
    const float* w2   = (const float*)d_in[5];
    const float* w3   = (const float*)d_in[6];
    float* out = (float*)d_out;

    // Scratch: d_out hosts xws [0,25.6M) and ea [25.6M,38.4M) (dead before
    // k_gather_n overwrites d_out). d_ws: inter | w1f 32K | w2f 32K | e1s 12.8M.
    _Float16* xws   = (_Float16*)d_out;
    _Float16* ea    = (_Float16*)d_out + (size_t)ND * D;
    float*    inter = (float*)d_ws;
    _Float16* w1f   = (_Float16*)((char*)d_ws + 256);
    _Float16* w2f   = (_Float16*)((char*)d_ws + 256 + 32768);
    _Float16* e1s   = (_Float16*)((char*)d_ws + 256 + 65536);

    int eg_grp = (NE + 63) / 64;         // 782
    int ng_grp = (ND + 63) / 64;         // 1563

    hipLaunchKernelGGL(k_prep,     dim3(65),             dim3(256), 0, stream, w1, w2, w3, w1f, w2f, inter);
    hipLaunchKernelGGL(k_xw,       dim3((ND + 63) / 64), dim3(256), 0, stream, x, w1f, inter, xws);
    hipLaunchKernelGGL(k_gather_e, dim3(eg_grp * 4),     dim3(256), 0, stream, seq, xws, ea);
    hipLaunchKernelGGL(k_gemm_e,   dim3((NE + 63) / 64), dim3(256), 0, stream, ea, w2f, e1s);
    hipLaunchKernelGGL(k_gather_n, dim3(ng_grp * 4),     dim3(256), 0, stream, useq, e1s, out);
}